// Round 4
// baseline (220.672 us; speedup 1.0000x reference)
//
#include <hip/hip_runtime.h>

#define BINS 10
#define ALPHA 0.75f

constexpr int NB    = 2048;   // pass-1 blocks
constexpr int NT    = 256;    // pass-1 threads per block (4 waves)
constexpr int ITERS = 8;      // float4 iterations per thread on the fast path
constexpr int NT2   = 1024;   // pass-2 threads (single block, 16 waves)

// Cumulative bin thresholds on u = diff*(2t-1):
//   g = sigmoid(-u) = 1/(1+e^u)  (monotone decreasing in u)
//   g >= k/10  <=>  u <= L_k,  L_k = ln((10-k)/k)
// bin(g) = #{k in 1..9 : u <= L_k}; per-bin values recovered in pass 2 by
// differencing the cumulative sums. No exp/rcp in the hot loop.
__device__ __constant__ float LTH[9] = {
    2.19722458f,  1.38629436f,  0.847297861f, 0.405465108f, 0.0f,
   -0.405465108f, -0.847297861f, -1.38629436f, -2.19722458f};

// cls[0] += loss (all elems); for k=1..9: p=(u<=L_k); cls[k]+=p?loss:0; cnt[k]+=p.
#define GHM_PROC(AX, BX, TX) do {                                    \
    float diff = (AX) - (BX);                                        \
    float nd   = -diff;                                              \
    bool  tt   = (TX) != 0;                                          \
    float u    = tt ? diff : nd;                                     \
    float loss = tt ? fmaxf(nd, 0.0f) : 0.0f;                        \
    cls[0] += loss;                                                  \
    _Pragma("unroll")                                                \
    for (int k = 1; k < BINS; ++k) {                                 \
      bool p = (u <= LTH[k - 1]);                                    \
      cls[k] += p ? loss : 0.0f;                                     \
      cnt[k] += (unsigned int)p;                                     \
    }                                                                \
  } while (0)

#define GHM_PROC4(AV, BV, TV) do {                                   \
    GHM_PROC((AV).x, (BV).x, (TV).x);                                \
    GHM_PROC((AV).y, (BV).y, (TV).y);                                \
    GHM_PROC((AV).z, (BV).z, (TV).z);                                \
    GHM_PROC((AV).w, (BV).w, (TV).w);                                \
  } while (0)

// Pass 1: fused elementwise + cumulative per-bin {count, loss-sum}.
// Fast path: explicit DEPTH-2 software pipeline — iteration k computes data
// loaded at k, while k+2's loads are already issued. sched_barrier(0) after
// each prefetch cluster forbids the scheduler from re-sinking the loads
// (round-3 failure mode: compiler minimized VGPRs and serialized
// load->drain->compute; counters showed latency-bound at 2.6 TB/s with
// VALUBusy 23% and HBM 16%). Compiler emits counted vmcnt(6) (never drains).
__global__ __launch_bounds__(NT) void ghm_pass1(
    const float* __restrict__ o1f, const float* __restrict__ o2f,
    const int* __restrict__ tgt, float* __restrict__ lsum_part,
    unsigned int* __restrict__ cnt_part, int n)
{
  const float4* o1 = reinterpret_cast<const float4*>(o1f);
  const float4* o2 = reinterpret_cast<const float4*>(o2f);
  const int4*   tg = reinterpret_cast<const int4*>(tgt);

  float        cls[BINS];   // cls[0]=total loss; cls[k] cumulative loss-sum
  unsigned int cnt[BINS];   // cnt[k], k>=1 cumulative counts; cnt[0] stays 0
#pragma unroll
  for (int b = 0; b < BINS; ++b) { cls[b] = 0.0f; cnt[b] = 0u; }

  if (n == NB * NT * ITERS * 4 && gridDim.x == NB) {
    // Block owns NT*ITERS consecutive float4s; thread strides by NT (coalesced).
    const int base = blockIdx.x * (NT * ITERS) + threadIdx.x;
    float4 a0 = o1[base];      float4 b0 = o2[base];      int4 t0 = tg[base];
    float4 a1 = o1[base + NT]; float4 b1 = o2[base + NT]; int4 t1 = tg[base + NT];
#pragma unroll
    for (int k = 0; k < ITERS - 2; ++k) {
      float4 a2 = o1[base + (k + 2) * NT];
      float4 b2 = o2[base + (k + 2) * NT];
      int4   t2 = tg[base + (k + 2) * NT];
      __builtin_amdgcn_sched_barrier(0);   // prefetch stays ABOVE compute
      GHM_PROC4(a0, b0, t0);
      a0 = a1; b0 = b1; t0 = t1;
      a1 = a2; b1 = b2; t1 = t2;
    }
    GHM_PROC4(a0, b0, t0);
    GHM_PROC4(a1, b1, t1);
  } else {
    // Generic grid-stride fallback (any n, any grid).
    const int tid = blockIdx.x * NT + threadIdx.x;
    const int stride = gridDim.x * NT;
    const int n4 = n >> 2;
    for (int i = tid; i < n4; i += stride) {
      float4 a  = o1[i];
      float4 bb = o2[i];
      int4   t  = tg[i];
      GHM_PROC4(a, bb, t);
    }
    if (tid == 0) {
      for (int i = n4 * 4; i < n; ++i) GHM_PROC(o1f[i], o2f[i], tgt[i]);
    }
  }

  // wave64 shuffle reduce, then cross-wave via LDS; one deterministic
  // partial per block (no atomics). Partials stored TRANSPOSED [BINS][nb]
  // so pass-2 reads are contiguous per bin.
  const int lane = threadIdx.x & 63;
  const int wv   = threadIdx.x >> 6;
  __shared__ float        s_ls[NT / 64][BINS];
  __shared__ unsigned int s_c [NT / 64][BINS];
#pragma unroll
  for (int b = 0; b < BINS; ++b) {
    float v = cls[b];
    unsigned int cv = cnt[b];
#pragma unroll
    for (int off = 32; off >= 1; off >>= 1) {
      v  += __shfl_down(v, off, 64);
      cv += __shfl_down(cv, off, 64);
    }
    if (lane == 0) { s_ls[wv][b] = v; s_c[wv][b] = cv; }
  }
  __syncthreads();
  if (threadIdx.x < BINS) {
    float v = 0.0f; unsigned int cv = 0u;
#pragma unroll
    for (int w = 0; w < NT / 64; ++w) { v += s_ls[w][threadIdx.x]; cv += s_c[w][threadIdx.x]; }
    lsum_part[threadIdx.x * gridDim.x + blockIdx.x] = v;
    cnt_part [threadIdx.x * gridDim.x + blockIdx.x] = cv;
  }
}

// Pass 2: one wide block reduces [BINS][nparts] cumulative partials in double
// (coalesced contiguous reads per bin), differences cumulative->per-bin,
// applies w[b] = max((f32)cnt,1)^-0.75, writes the scalar mean.
__global__ __launch_bounds__(NT2) void ghm_pass2(
    const float* __restrict__ lsum_part, const unsigned int* __restrict__ cnt_part,
    float* __restrict__ out, int nparts, int n)
{
  double             cls[BINS];
  unsigned long long cc [BINS];
#pragma unroll
  for (int b = 0; b < BINS; ++b) { cls[b] = 0.0; cc[b] = 0ull; }

  for (int i = threadIdx.x; i < nparts; i += NT2) {
#pragma unroll
    for (int b = 0; b < BINS; ++b) {
      cls[b] += (double)lsum_part[b * nparts + i];
      cc[b]  += (unsigned long long)cnt_part[b * nparts + i];
    }
  }

  const int lane = threadIdx.x & 63;
  const int wv   = threadIdx.x >> 6;
  __shared__ double             s_ls[NT2 / 64][BINS];
  __shared__ unsigned long long s_c [NT2 / 64][BINS];
#pragma unroll
  for (int b = 0; b < BINS; ++b) {
    double v = cls[b];
    unsigned long long cv = cc[b];
#pragma unroll
    for (int off = 32; off >= 1; off >>= 1) {
      v  += __shfl_down(v, off, 64);
      cv += __shfl_down(cv, off, 64);
    }
    if (lane == 0) { s_ls[wv][b] = v; s_c[wv][b] = cv; }
  }
  __syncthreads();
  if (threadIdx.x == 0) {
    double             CLS[BINS + 1];
    unsigned long long CC [BINS + 1];
#pragma unroll
    for (int b = 0; b < BINS; ++b) {
      double lv = 0.0; unsigned long long cv = 0ull;
#pragma unroll
      for (int w = 0; w < NT2 / 64; ++w) { lv += s_ls[w][b]; cv += s_c[w][b]; }
      CLS[b] = lv; CC[b] = cv;
    }
    CLS[BINS] = 0.0; CC[BINS] = 0ull;
    CC[0] = (unsigned long long)n;  // cumulative count at k=0 is all elements

    double total = 0.0;
#pragma unroll
    for (int b = 0; b < BINS; ++b) {
      double lsb            = CLS[b] - CLS[b + 1];
      unsigned long long cb = CC[b] - CC[b + 1];
      float cf  = (float)cb;           // counts.astype(float32)
      float tot = fmaxf(cf, 1.0f);     // clip(counts, 1.0)
      float wgt = powf(tot, -ALPHA);   // tot ** -0.75
      total += lsb * (double)wgt;
    }
    out[0] = (float)(total / (double)n);
  }
}

extern "C" void kernel_launch(void* const* d_in, const int* in_sizes, int n_in,
                              void* d_out, int out_size, void* d_ws, size_t ws_size,
                              hipStream_t stream) {
  const float* o1  = (const float*)d_in[0];
  const float* o2  = (const float*)d_in[1];
  const int*   tgt = (const int*)d_in[2];
  float* out = (float*)d_out;
  const int n = in_sizes[0];

  // ws layout: [BINS][nb] f32 cumulative loss partials, then [BINS][nb] u32
  // cumulative count partials. Every slot written by pass1 (no zero-init need).
  int nb = NB;
  size_t need = (size_t)nb * BINS * (sizeof(float) + sizeof(unsigned int));
  while (nb > 1 && need > ws_size) { nb >>= 1; need >>= 1; }  // safety only
  float* lsum_part = (float*)d_ws;
  unsigned int* cnt_part = (unsigned int*)((char*)d_ws + (size_t)nb * BINS * sizeof(float));

  ghm_pass1<<<nb, NT, 0, stream>>>(o1, o2, tgt, lsum_part, cnt_part, n);
  ghm_pass2<<<1, NT2, 0, stream>>>(lsum_part, cnt_part, out, nb, n);
}

// Round 5
// 218.701 us; speedup vs baseline: 1.0090x; 1.0090x over previous
//
#include <hip/hip_runtime.h>

#define BINS 10
#define ALPHA 0.75f

constexpr int NB    = 2048;     // pass-1 blocks
constexpr int NT    = 256;      // threads per block (4 waves)
constexpr int NWV   = NT / 64;  // waves per block
constexpr int ITERS = 8;        // float4 steps per thread (NB*NT*ITERS*4 == 2^24)

// Cumulative bin thresholds on u = diff*(2t-1):
//   g = sigmoid(-u); g >= k/10  <=>  u <= L_k = ln((10-k)/k)
// bin(g) = #{k: u <= L_k}; per-bin recovered by differencing in finalize.
__device__ constexpr float LTH[9] = {
    2.19722458f,  1.38629436f,  0.847297861f, 0.405465108f, 0.0f,
   -0.405465108f, -0.847297861f, -1.38629436f, -2.19722458f};

#define GHM_PROC(AX, BX, TX) do {                                    \
    float diff = (AX) - (BX);                                        \
    float nd   = -diff;                                              \
    bool  tt   = (TX) != 0;                                          \
    float u    = tt ? diff : nd;                                     \
    float loss = tt ? fmaxf(nd, 0.0f) : 0.0f;                        \
    cls[0] += loss;                                                  \
    _Pragma("unroll")                                                \
    for (int k = 1; k < BINS; ++k) {                                 \
      bool p = (u <= LTH[k - 1]);                                    \
      cls[k] += p ? loss : 0.0f;                                     \
      cnt[k] += (unsigned int)p;                                     \
    }                                                                \
  } while (0)

#define GHM_PROC4(AV, BV, TV) do {                                   \
    GHM_PROC((AV).x, (BV).x, (TV).x);                                \
    GHM_PROC((AV).y, (BV).y, (TV).y);                                \
    GHM_PROC((AV).z, (BV).z, (TV).z);                                \
    GHM_PROC((AV).w, (BV).w, (TV).w);                                \
  } while (0)

// Async global->LDS DMA, 16 B per lane. LDS dest is WAVE-UNIFORM base +
// lane*16 (m104); global src is per-lane. No destination VGPRs are consumed,
// so the compiler cannot shrink the pipeline depth (rounds 3-4 failure mode).
__device__ __forceinline__ void gl_lds16(const void* g, void* l) {
  __builtin_amdgcn_global_load_lds(
      (const __attribute__((address_space(1))) unsigned int*)g,
      (__attribute__((address_space(3))) unsigned int*)l, 16, 0, 0);
}

// Pass 1: triple-buffered, WAVE-PRIVATE LDS staging (no __syncthreads in the
// loop), 2-step lookahead, counted inline-asm vmcnt(3) (drains to 0 only at
// the tail). Each wave stages its own 64 float4s per stream per step and
// consumes only what it staged. Per-bin cumulative {count, loss-sum} in
// registers (static indexing), then wave/LDS reduce and ONE atomicAdd per
// bin per block (double for loss, u32 for counts).
__global__ __launch_bounds__(NT) void ghm_pass1(
    const float* __restrict__ o1f, const float* __restrict__ o2f,
    const int* __restrict__ tgt, double* __restrict__ gls,
    unsigned int* __restrict__ gcnt, int n)
{
  const float4* o1 = reinterpret_cast<const float4*>(o1f);
  const float4* o2 = reinterpret_cast<const float4*>(o2f);
  const int4*   tg = reinterpret_cast<const int4*>(tgt);

  float        cls[BINS];
  unsigned int cnt[BINS];
#pragma unroll
  for (int b = 0; b < BINS; ++b) { cls[b] = 0.0f; cnt[b] = 0u; }

  const int lane = threadIdx.x & 63;
  const int wv   = threadIdx.x >> 6;

  // 3 bufs x 4 waves x 64 lanes x 16 B = 12 KB per stream, 36 KB total.
  __shared__ float4 La[3][NWV][64];
  __shared__ float4 Lb[3][NWV][64];
  __shared__ int4   Lt[3][NWV][64];

  if (n == NB * NT * ITERS * 4 && gridDim.x == NB) {
    const int gbase = blockIdx.x * (NT * ITERS);

#define STAGE(K, BUF) do {                                            \
      const int gi = gbase + (K) * NT + (int)threadIdx.x;             \
      gl_lds16(&o1[gi], &La[BUF][wv][0]);                             \
      gl_lds16(&o2[gi], &Lb[BUF][wv][0]);                             \
      gl_lds16(&tg[gi], &Lt[BUF][wv][0]);                             \
    } while (0)

    // Prologue: 2 steps in flight (6 outstanding DMAs per wave).
    STAGE(0, 0);
    STAGE(1, 1);

#pragma unroll
    for (int k = 0; k < ITERS; ++k) {
      // Oldest 3 outstanding = step k's DMAs. vmcnt retires in issue order,
      // so vmcnt(3) == "step k landed in LDS". Never drain to 0 mid-loop.
      if (k == ITERS - 1) asm volatile("s_waitcnt vmcnt(0)" ::: "memory");
      else                asm volatile("s_waitcnt vmcnt(3)" ::: "memory");
      const int buf = k % 3;
      float4 a = La[buf][wv][lane];
      float4 b = Lb[buf][wv][lane];
      int4   t = Lt[buf][wv][lane];
      // Refill buf (k+2)%3 == (k-1)%3: its step-(k-1) reads were issued a
      // full iteration ago (in-order LDS pipe) and DMA data lands >=300 cyc
      // after issue — no overwrite hazard, no barrier needed (wave-private).
      if (k + 2 < ITERS) { STAGE(k + 2, (k + 2) % 3); }
      GHM_PROC4(a, b, t);
    }
#undef STAGE
  } else {
    // Generic grid-stride fallback (any n / grid): plain vector loads.
    const int tid = blockIdx.x * NT + threadIdx.x;
    const int stride = gridDim.x * NT;
    const int n4 = n >> 2;
    for (int i = tid; i < n4; i += stride) {
      float4 a  = o1[i];
      float4 bb = o2[i];
      int4   t  = tg[i];
      GHM_PROC4(a, bb, t);
    }
    if (tid == 0) {
      for (int i = n4 * 4; i < n; ++i) GHM_PROC(o1f[i], o2f[i], tgt[i]);
    }
  }

  // Wave shuffle reduce -> cross-wave LDS reduce -> one atomic per bin.
  __shared__ float        s_ls[NWV][BINS];
  __shared__ unsigned int s_c [NWV][BINS];
#pragma unroll
  for (int b = 0; b < BINS; ++b) {
    float v = cls[b];
    unsigned int cv = cnt[b];
#pragma unroll
    for (int off = 32; off >= 1; off >>= 1) {
      v  += __shfl_down(v, off, 64);
      cv += __shfl_down(cv, off, 64);
    }
    if (lane == 0) { s_ls[wv][b] = v; s_c[wv][b] = cv; }
  }
  __syncthreads();
  if (threadIdx.x < BINS) {
    float v = 0.0f; unsigned int cv = 0u;
#pragma unroll
    for (int w = 0; w < NWV; ++w) { v += s_ls[w][threadIdx.x]; cv += s_c[w][threadIdx.x]; }
    atomicAdd(&gls[threadIdx.x], (double)v);
    if (cv) atomicAdd(&gcnt[threadIdx.x], cv);
  }
}

// Finalize: 1 wave. Difference cumulative sums, apply w[b] =
// max((f32)count,1)^-0.75 (matching reference's f32 cast), write the mean.
__global__ void ghm_final(const double* __restrict__ gls,
                          const unsigned int* __restrict__ gcnt,
                          float* __restrict__ out, int n)
{
  if (threadIdx.x == 0) {
    double             CLS[BINS + 1];
    unsigned long long CC [BINS + 1];
#pragma unroll
    for (int b = 0; b < BINS; ++b) { CLS[b] = gls[b]; CC[b] = gcnt[b]; }
    CLS[BINS] = 0.0; CC[BINS] = 0ull;
    CC[0] = (unsigned long long)n;   // cumulative count at k=0 = all elements

    double total = 0.0;
#pragma unroll
    for (int b = 0; b < BINS; ++b) {
      double lsb            = CLS[b] - CLS[b + 1];
      unsigned long long cb = CC[b] - CC[b + 1];
      float cf  = (float)cb;           // counts.astype(float32)
      float tot = fmaxf(cf, 1.0f);     // clip(counts, 1.0)
      float wgt = powf(tot, -ALPHA);   // tot ** -0.75
      total += lsb * (double)wgt;
    }
    out[0] = (float)(total / (double)n);
  }
}

extern "C" void kernel_launch(void* const* d_in, const int* in_sizes, int n_in,
                              void* d_out, int out_size, void* d_ws, size_t ws_size,
                              hipStream_t stream) {
  const float* o1  = (const float*)d_in[0];
  const float* o2  = (const float*)d_in[1];
  const int*   tgt = (const int*)d_in[2];
  float* out = (float*)d_out;
  const int n = in_sizes[0];

  // ws layout: double gls[10] (80 B) then u32 gcnt[10] (40 B). Zeroed each
  // call (harness poisons ws with 0xAA); memsetAsync is graph-capturable.
  double*       gls  = (double*)d_ws;
  unsigned int* gcnt = (unsigned int*)((char*)d_ws + BINS * sizeof(double));
  hipMemsetAsync(d_ws, 0, BINS * (sizeof(double) + sizeof(unsigned int)), stream);

  ghm_pass1<<<NB, NT, 0, stream>>>(o1, o2, tgt, gls, gcnt, n);
  ghm_final<<<1, 64, 0, stream>>>(gls, gcnt, out, n);
}